// Round 2
// baseline (466.426 us; speedup 1.0000x reference)
//
#include <hip/hip_runtime.h>
#include <hip/hip_bf16.h>
#include <math.h>

#define HW   4096
#define CCH  256
#define NE   8
#define HID  512
#define NTOK 65536
#define PADH 260   // Hs row pitch (elems): +4 pad -> conflict-free writes, low-conflict reads

typedef short s16x8 __attribute__((ext_vector_type(8)));
typedef float f32x4 __attribute__((ext_vector_type(4)));

// Fast exact-enough GELU: v * sigmoid(2u), u = 0.79788456*(v + 0.044715 v^3).
__device__ __forceinline__ float fast_gelu(float v) {
    float v2 = v * v;
    float s  = v * fmaf(0.10294324f, v2, 2.3022079f);  // 2*log2e*0.79788456*(v+0.044715v^3)
    float e  = exp2f(-s);                               // = exp(-2u)
    return v * __builtin_amdgcn_rcpf(1.0f + e);         // v * sigmoid(2u)
}

// ---------------- K transpose+cast for BOTH weights in one launch -----------
// blocks [0,256): W1 (E,256,512)->(E,512,256); blocks [256,512): W2 (E,512,256)->(E,256,512)
__global__ __launch_bounds__(256) void k_transpose_both(
    const float* __restrict__ W1, const float* __restrict__ W2,
    __hip_bfloat16* __restrict__ w1t, __hip_bfloat16* __restrict__ w2t)
{
    __shared__ float t[64][65];
    int bb = blockIdx.x;
    const float* in; __hip_bfloat16* out; int R, CC;
    if (bb < 256) { in = W1; out = w1t; R = 256; CC = 512; }
    else          { in = W2; out = w2t; R = 512; CC = 256; bb -= 256; }
    int tilesC = CC >> 6;
    int per = (R >> 6) * tilesC;
    int e = bb / per, tt = bb % per;
    int r0 = (tt / tilesC) << 6, c0 = (tt % tilesC) << 6;
    const float* ip = in + (size_t)e * R * CC;
    __hip_bfloat16* op = out + (size_t)e * R * CC;
    int lane = threadIdx.x & 63, g = threadIdx.x >> 6;
    for (int i = 0; i < 16; i++) {
        int r = i * 4 + g;
        t[r][lane] = ip[(size_t)(r0 + r) * CC + c0 + lane];
    }
    __syncthreads();
    for (int i = 0; i < 16; i++) {
        int r = i * 4 + g;
        op[(size_t)(c0 + r) * R + r0 + lane] = __float2bfloat16(t[lane][r]);
    }
}

// ---------------- K0: x transpose -> tokens bf16, fp32 router, top2 ---------
__global__ __launch_bounds__(256) void k_router(
    const float* __restrict__ x, const float* __restrict__ Wr, const float* __restrict__ br,
    __hip_bfloat16* __restrict__ tokens, int* __restrict__ pair, float2* __restrict__ wts,
    int* __restrict__ meta /* counts at [0..8) */)
{
    __shared__ float xt[CCH][65];
    __shared__ float wr[CCH][NE];
    __shared__ float lg[64][NE];
    __shared__ int lc[NE];
    int tid = threadIdx.x;
    int n0 = blockIdx.x * 64;
    int b = n0 >> 12, p0 = n0 & 4095;
    const float* xb = x + (size_t)b * CCH * HW + p0;
    for (int i = tid; i < CCH * NE; i += 256) ((float*)wr)[i] = Wr[i];
    if (tid < NE) lc[tid] = 0;
    int lane = tid & 63, wv = tid >> 6;
    for (int i = 0; i < 64; i++) {
        int c = i * 4 + wv;
        xt[c][lane] = xb[(size_t)c * HW + lane];
    }
    __syncthreads();
    float a0 = br[2 * wv], a1 = br[2 * wv + 1];
    for (int c = 0; c < CCH; c++) {
        float xv = xt[c][lane];
        a0 = fmaf(xv, wr[c][2 * wv], a0);
        a1 = fmaf(xv, wr[c][2 * wv + 1], a1);
    }
    lg[lane][2 * wv] = a0;
    lg[lane][2 * wv + 1] = a1;
    __syncthreads();
    if (wv == 0) {
        float v0 = -1e30f, v1 = -1e30f; int i0 = 0, i1 = 0;
        for (int e = 0; e < NE; e++) {
            float l = lg[lane][e];
            if (l > v0)      { v1 = v0; i1 = i0; v0 = l; i0 = e; }
            else if (l > v1) { v1 = l; i1 = e; }
        }
        float e1 = expf(v1 - v0);
        float s = 1.0f + e1;
        wts[n0 + lane] = make_float2(1.0f / s, e1 / s);
        pair[n0 + lane] = i0 | (i1 << 8);
        atomicAdd(&lc[i0], 1);
        atomicAdd(&lc[i1], 1);
    }
    __syncthreads();
    if (tid < NE && lc[tid] > 0) atomicAdd(&meta[tid], lc[tid]);
    for (int r = 0; r < 64; r++)
        tokens[(size_t)(n0 + r) * CCH + tid] = __float2bfloat16(xt[tid][r]);
}

// ---------------- K2: scatter tokens into per-expert lists ------------------
// meta: [0..8) counts, [8..16) cursors, [16..25) offsets, [25..34) tilestart, [34] total
// The scan (offsets/tilestarts) is computed per-block in LDS from the final
// counts; block 0 additionally publishes it to meta for k_expert. Saves the
// separate k_scan launch. Tiles are 32 tokens now.
__global__ __launch_bounds__(256) void k_scatter(
    const int* __restrict__ pair, const float2* __restrict__ wts,
    int* __restrict__ meta, int* __restrict__ assign_tok, float* __restrict__ assign_w,
    int2* __restrict__ tok_slots)
{
    __shared__ int lcount[NE];
    __shared__ int lbase[NE];
    __shared__ int soff[NE];
    int tid = threadIdx.x;
    int n = blockIdx.x * 256 + tid;
    if (tid < NE) lcount[tid] = 0;
    __syncthreads();
    int pr = pair[n];
    int e0 = pr & 0xff, e1 = (pr >> 8) & 0xff;
    int p0 = atomicAdd(&lcount[e0], 1);
    int p1 = atomicAdd(&lcount[e1], 1);
    __syncthreads();
    if (tid == 0) {
        int off = 0, toff = 0;
        for (int ee = 0; ee < NE; ee++) {
            soff[ee] = off;
            int c = meta[ee];
            if (blockIdx.x == 0) { meta[16 + ee] = off; meta[25 + ee] = toff; }
            off += c;
            toff += (c + 31) >> 5;
        }
        if (blockIdx.x == 0) { meta[24] = off; meta[33] = toff; meta[34] = toff; }
    }
    if (tid < NE) lbase[tid] = atomicAdd(&meta[8 + tid], lcount[tid]);
    __syncthreads();
    float2 w = wts[n];
    int s0 = soff[e0] + lbase[e0] + p0;
    int s1 = soff[e1] + lbase[e1] + p1;
    assign_tok[s0] = n; assign_w[s0] = w.x;
    assign_tok[s1] = n; assign_w[s1] = w.y;
    tok_slots[n] = make_int2(s0, s1);
}

// ---------------- K3: grouped fused MLP (the hot kernel) --------------------
// Round-2 restructure: 256 threads = 4 waves, 32-token tile, LDS 33.3 KB
// -> 4 independent blocks/CU (was 2 @ 66.5 KB). Same 16-wave/CU total but 4
// decorrelated barrier groups: when one block drains vmcnt at a barrier, three
// others compute. GEMMs run as 2 nt-pair passes (2 mt x 2 streams x 8 kk);
// each pass's first B-frags are issued in the PREVIOUS pass's tail so they
// complete during the intervening barrier drain.
__global__ __launch_bounds__(256, 4) void k_expert(
    const __hip_bfloat16* __restrict__ tokens,
    const __hip_bfloat16* __restrict__ w1t,   // (E, HID, C)  = W1^T per expert
    const __hip_bfloat16* __restrict__ w2t,   // (E, C, HID)  = W2^T per expert
    const float* __restrict__ b1, const float* __restrict__ b2,
    const int* __restrict__ meta,
    const int* __restrict__ assign_tok, const float* __restrict__ assign_w,
    __hip_bfloat16* __restrict__ ybuf)
{
    // A tile, frag-linear: 16B unit U = mt*512 + (kk*4+quad)*16 + l15
    __shared__ __align__(16) __hip_bfloat16 Af[32 * 256];      // 16 KB
    __shared__ __align__(16) __hip_bfloat16 Hs[32 * PADH];     // 16.6 KB
    __shared__ float wrow[32];
    __shared__ int trow[32];

    int total = meta[34];
    int bid = blockIdx.x;
    if (bid >= total) return;
    int e = 0;
    while (e < 7 && bid >= meta[25 + e + 1]) e++;
    int tile = bid - meta[25 + e];
    int cnt = meta[e];
    int r0 = tile << 5;
    int abase = meta[16 + e] + r0;
    int nrows = cnt - r0; if (nrows > 32) nrows = 32;

    int tid = threadIdx.x;
    if (tid < 32) {
        if (tid < nrows) { trow[tid] = assign_tok[abase + tid]; wrow[tid] = assign_w[abase + tid]; }
        else             { trow[tid] = 0; wrow[tid] = 0.0f; }
    }

    // ---- stage A tile (frag-linear, lane-linear 16B writes => no conflicts).
    // Token rows fetched directly from assign_tok (no barrier dependency).
    {
        int rA = tid & 15, rB = 16 + (tid & 15);
        int tA = (rA < nrows) ? assign_tok[abase + rA] : 0;
        int tB = (rB < nrows) ? assign_tok[abase + rB] : 0;
        uint4* dst = (uint4*)Af;
#pragma unroll
        for (int j = 0; j < 4; j++) {
            int tr = (j & 1) ? tB : tA;
            int chunk = (tid >> 4) + (j >> 1) * 16;
            dst[(j & 1) * 512 + (j >> 1) * 256 + tid] =
                ((const uint4*)(tokens + (size_t)tr * CCH))[chunk];
        }
    }

    int lane = tid & 63, wv = tid >> 6;      // wv in [0,4)
    int quad = lane >> 4, l15 = lane & 15;

    const __hip_bfloat16* w1e = w1t + (size_t)e * HID * CCH;
    const __hip_bfloat16* w2e = w2t + (size_t)e * CCH * HID;
    const float* b1e = b1 + e * HID;

    const s16x8* apb = (const s16x8*)Af + quad * 16 + l15;   // + mt*512 + kk*64

    f32x4 oacc[4][2];
#pragma unroll
    for (int i = 0; i < 4; i++)
#pragma unroll
        for (int j = 0; j < 2; j++) oacc[i][j] = (f32x4){0.f, 0.f, 0.f, 0.f};

// B stream pointers: pass covers rows (wv*64 + ROW .. +15) and (+16 more)
#define G1P(H, ROW) ((const s16x8*)(w1e + (size_t)((H) * 256 + wv * 64 + (ROW) + l15) * CCH) + quad)
#define G2P(H, ROW) ((const s16x8*)(w2e + (size_t)(wv * 64 + (ROW) + l15) * HID + (H) * 256) + quad)
#define LOADNEXT(P0, P1) { q0 = (P0); q1 = (P1); bf0 = q0[0]; bf1 = q1[0]; }

// One GEMM pass: 8 kk steps, 2 mt x 2 streams, depth-1 in-loop prefetch,
// TAIL issues the NEXT pass's first frags (completes across the barrier drain).
#define PASS(A0EXPR, A1EXPR, ACC0, ACC1, TAIL)                                 \
    {                                                                          \
        _Pragma("unroll")                                                      \
        for (int kk = 0; kk < 8; kk++) {                                       \
            s16x8 bn0, bn1;                                                    \
            if (kk < 7) { bn0 = q0[(kk + 1) * 4]; bn1 = q1[(kk + 1) * 4]; }    \
            s16x8 a0 = (A0EXPR), a1 = (A1EXPR);                                \
            __builtin_amdgcn_s_setprio(1);                                     \
            ACC0[0] = __builtin_amdgcn_mfma_f32_16x16x32_bf16(a0, bf0, ACC0[0], 0, 0, 0); \
            ACC1[0] = __builtin_amdgcn_mfma_f32_16x16x32_bf16(a0, bf1, ACC1[0], 0, 0, 0); \
            ACC0[1] = __builtin_amdgcn_mfma_f32_16x16x32_bf16(a1, bf0, ACC0[1], 0, 0, 0); \
            ACC1[1] = __builtin_amdgcn_mfma_f32_16x16x32_bf16(a1, bf1, ACC1[1], 0, 0, 0); \
            __builtin_amdgcn_s_setprio(0);                                     \
            if (kk < 7) { bf0 = bn0; bf1 = bn1; }                              \
        }                                                                      \
        TAIL                                                                   \
    }

#define A1_0 apb[kk * 64]
#define A1_1 apb[512 + kk * 64]
#define A2_0 (*(const s16x8*)(Hs + (size_t)l15 * PADH + kk * 32 + quad * 8))
#define A2_1 (*(const s16x8*)(Hs + (size_t)(16 + l15) * PADH + kk * 32 + quad * 8))

    const s16x8 *q0 = G1P(0, 0), *q1 = G1P(0, 16);
    s16x8 bf0 = q0[0], bf1 = q1[0];

    __syncthreads();   // A tile + trow/wrow visible; bf0/bf1 complete via drain

#pragma unroll
    for (int h = 0; h < 2; h++) {
        f32x4 hacc[4][2];
#pragma unroll
        for (int i = 0; i < 4; i++)
#pragma unroll
            for (int j = 0; j < 2; j++) hacc[i][j] = (f32x4){0.f, 0.f, 0.f, 0.f};

        // ---- GEMM1: two nt-pair passes over K=256
        PASS(A1_0, A1_1, hacc[0], hacc[1], LOADNEXT(G1P(h, 32), G1P(h, 48)));
        PASS(A1_0, A1_1, hacc[2], hacc[3], LOADNEXT(G2P(h, 0), G2P(h, 16)));

        // GELU biases issued before the barrier (complete in the drain)
        float bias0 = b1e[h * 256 + wv * 64 + l15];
        float bias1 = b1e[h * 256 + wv * 64 + 16 + l15];
        float bias2 = b1e[h * 256 + wv * 64 + 32 + l15];
        float bias3 = b1e[h * 256 + wv * 64 + 48 + l15];

        __syncthreads();   // (h=1: GEMM2 of h=0 done reading Hs)
        // ---- bias + fast GELU -> Hs
#pragma unroll
        for (int nt = 0; nt < 4; nt++) {
            float bias = (nt == 0) ? bias0 : (nt == 1) ? bias1 : (nt == 2) ? bias2 : bias3;
            int cl = wv * 64 + nt * 16 + l15;
#pragma unroll
            for (int mt = 0; mt < 2; mt++)
#pragma unroll
                for (int r = 0; r < 4; r++) {
                    int row = mt * 16 + quad * 4 + r;
                    float v = hacc[nt][mt][r] + bias;
                    Hs[row * PADH + cl] = __float2bfloat16(fast_gelu(v));
                }
        }
        __syncthreads();

        // ---- GEMM2: two nt-pair passes, A = Hs rows (LDS), K = this half
        PASS(A2_0, A2_1, oacc[0], oacc[1], LOADNEXT(G2P(h, 32), G2P(h, 48)));
        if (h == 0) {
            PASS(A2_0, A2_1, oacc[2], oacc[3], LOADNEXT(G1P(1, 0), G1P(1, 16)));
        } else {
            PASS(A2_0, A2_1, oacc[2], oacc[3], );
        }
    }

    // ---- epilogue: (acc + b2) * route_weight -> ybuf[slot][c] bf16
    const float* b2e = b2 + e * CCH;
    float bb0 = b2e[wv * 64 + l15];
    float bb1 = b2e[wv * 64 + 16 + l15];
    float bb2 = b2e[wv * 64 + 32 + l15];
    float bb3 = b2e[wv * 64 + 48 + l15];
#pragma unroll
    for (int nt = 0; nt < 4; nt++) {
        float bias = (nt == 0) ? bb0 : (nt == 1) ? bb1 : (nt == 2) ? bb2 : bb3;
        int cc = wv * 64 + nt * 16 + l15;
#pragma unroll
        for (int mt = 0; mt < 2; mt++) {
#pragma unroll
            for (int r = 0; r < 4; r++) {
                int row = mt * 16 + quad * 4 + r;
                if (row < nrows) {
                    float v = (oacc[nt][mt][r] + bias) * wrow[row];
                    ybuf[(size_t)(abase + row) * CCH + cc] = __float2bfloat16(v);
                }
            }
        }
    }
#undef G1P
#undef G2P
#undef LOADNEXT
#undef PASS
#undef A1_0
#undef A1_1
#undef A2_0
#undef A2_1
}

// ---------------- K4: combine two expert outputs, transpose back, residual --
__global__ __launch_bounds__(256) void k_combine(
    const float* __restrict__ x, const __hip_bfloat16* __restrict__ ybuf,
    const int2* __restrict__ tok_slots, const float* __restrict__ scale,
    float* __restrict__ out)
{
    __shared__ float moe[CCH][65];
    __shared__ int2 slots[64];
    int tid = threadIdx.x;
    int n0 = blockIdx.x * 64;
    if (tid < 64) slots[tid] = tok_slots[n0 + tid];
    __syncthreads();
    for (int r = 0; r < 64; r++) {
        int2 s = slots[r];
        float y = __bfloat162float(ybuf[(size_t)s.x * CCH + tid]) +
                  __bfloat162float(ybuf[(size_t)s.y * CCH + tid]);
        moe[tid][r] = y;
    }
    __syncthreads();
    float sc = scale[0];
    int b = n0 >> 12, p0 = n0 & 4095;
    const float* xb = x + (size_t)b * CCH * HW + p0;
    float* ob = out + (size_t)b * CCH * HW + p0;
    int lane = tid & 63, wv = tid >> 6;
    for (int i = 0; i < 64; i++) {
        int c = i * 4 + wv;
        ob[(size_t)c * HW + lane] = xb[(size_t)c * HW + lane] + sc * moe[c][lane];
    }
}

// ---------------- launch ----------------------------------------------------
extern "C" void kernel_launch(void* const* d_in, const int* in_sizes, int n_in,
                              void* d_out, int out_size, void* d_ws, size_t ws_size,
                              hipStream_t stream)
{
    const float* x     = (const float*)d_in[0];
    const float* Wr    = (const float*)d_in[1];
    const float* br    = (const float*)d_in[2];
    const float* W1    = (const float*)d_in[3];
    const float* b1    = (const float*)d_in[4];
    const float* W2    = (const float*)d_in[5];
    const float* b2    = (const float*)d_in[6];
    const float* scale = (const float*)d_in[7];
    float* out = (float*)d_out;

    char* ws = (char*)d_ws;
    __hip_bfloat16* tokens = (__hip_bfloat16*)(ws);                 // 33,554,432 B
    __hip_bfloat16* w1t    = (__hip_bfloat16*)(ws + 33554432);      //  2,097,152 B
    __hip_bfloat16* w2t    = (__hip_bfloat16*)(ws + 35651584);      //  2,097,152 B
    __hip_bfloat16* ybuf   = (__hip_bfloat16*)(ws + 37748736);      // 67,108,864 B
    int*    assign_tok = (int*)   (ws + 104857600);                 //    524,288 B
    float*  assign_w   = (float*) (ws + 105381888);                 //    524,288 B
    int2*   tok_slots  = (int2*)  (ws + 105906176);                 //    524,288 B
    int*    pair       = (int*)   (ws + 106430464);                 //    262,144 B
    float2* wts        = (float2*)(ws + 106692608);                 //    524,288 B
    int*    meta       = (int*)   (ws + 107216896);                 //        256 B

    hipMemsetAsync(meta, 0, 64, stream);  // counts + cursors
    k_transpose_both<<<512, 256, 0, stream>>>(W1, W2, w1t, w2t);
    k_router<<<1024, 256, 0, stream>>>(x, Wr, br, tokens, pair, wts, meta);
    k_scatter<<<256, 256, 0, stream>>>(pair, wts, meta, assign_tok, assign_w, tok_slots);
    k_expert<<<4104, 256, 0, stream>>>(tokens, w1t, w2t, b1, b2, meta,
                                       assign_tok, assign_w, ybuf);
    k_combine<<<1024, 256, 0, stream>>>(x, ybuf, tok_slots, scale, out);
}

// Round 3
// 341.222 us; speedup vs baseline: 1.3669x; 1.3669x over previous
//
#include <hip/hip_runtime.h>
#include <hip/hip_bf16.h>
#include <math.h>

#define HW   4096
#define CCH  256
#define NE   8
#define HID  512
#define NTOK 65536
#define PADH 260   // Hs row pitch (elems): +4 pad -> conflict-free writes, 4-way reads

typedef short s16x8 __attribute__((ext_vector_type(8)));
typedef float f32x4 __attribute__((ext_vector_type(4)));
typedef unsigned short u16x8 __attribute__((ext_vector_type(8)));

// Fast exact-enough GELU: v * sigmoid(2u), u = 0.79788456*(v + 0.044715 v^3).
__device__ __forceinline__ float fast_gelu(float v) {
    float v2 = v * v;
    float s  = v * fmaf(0.10294324f, v2, 2.3022079f);  // 2*log2e*0.79788456*(v+0.044715v^3)
    float e  = exp2f(-s);                               // = exp(-2u)
    return v * __builtin_amdgcn_rcpf(1.0f + e);         // v * sigmoid(2u)
}

__device__ __forceinline__ float bfbits2f(unsigned short h) {
    return __uint_as_float(((unsigned)h) << 16);
}

// ---------------- K transpose+cast for BOTH weights (+ meta zero) -----------
// blocks [0,256): W1 (E,256,512)->(E,512,256); blocks [256,512): W2 -> (E,256,512)
__global__ __launch_bounds__(256) void k_transpose_both(
    const float* __restrict__ W1, const float* __restrict__ W2,
    __hip_bfloat16* __restrict__ w1t, __hip_bfloat16* __restrict__ w2t,
    int* __restrict__ meta)
{
    __shared__ float t[64][65];
    if (blockIdx.x == 0 && threadIdx.x < 16) meta[threadIdx.x] = 0;  // counts+cursors
    int bb = blockIdx.x;
    const float* in; __hip_bfloat16* out; int R, CC;
    if (bb < 256) { in = W1; out = w1t; R = 256; CC = 512; }
    else          { in = W2; out = w2t; R = 512; CC = 256; bb -= 256; }
    int tilesC = CC >> 6;
    int per = (R >> 6) * tilesC;
    int e = bb / per, tt = bb % per;
    int r0 = (tt / tilesC) << 6, c0 = (tt % tilesC) << 6;
    const float* ip = in + (size_t)e * R * CC;
    __hip_bfloat16* op = out + (size_t)e * R * CC;
    int lane = threadIdx.x & 63, g = threadIdx.x >> 6;
    for (int i = 0; i < 16; i++) {
        int r = i * 4 + g;
        t[r][lane] = ip[(size_t)(r0 + r) * CC + c0 + lane];
    }
    __syncthreads();
    for (int i = 0; i < 16; i++) {
        int r = i * 4 + g;
        op[(size_t)(c0 + r) * R + r0 + lane] = __float2bfloat16(t[lane][r]);
    }
}

// ---------------- K0: x transpose -> tokens bf16, fp32 router, top2 ---------
__global__ __launch_bounds__(256) void k_router(
    const float* __restrict__ x, const float* __restrict__ Wr, const float* __restrict__ br,
    __hip_bfloat16* __restrict__ tokens, int* __restrict__ pair, float2* __restrict__ wts,
    int* __restrict__ meta /* counts at [0..8) */)
{
    __shared__ float xt[CCH][66];   // pitch 66: float2-aligned rows, 2-way banks on reads
    __shared__ float wr[CCH][NE];
    __shared__ float lg[64][NE];
    __shared__ int lc[NE];
    int tid = threadIdx.x;
    int n0 = blockIdx.x * 64;
    int b = n0 >> 12, p0 = n0 & 4095;
    const float* xb = x + (size_t)b * CCH * HW + p0;
    for (int i = tid; i < CCH * NE; i += 256) ((float*)wr)[i] = Wr[i];
    if (tid < NE) lc[tid] = 0;
    int lane = tid & 63, wv = tid >> 6;
    // float2-vectorized staged read: 32 iterations (was 64 scalar)
    {
        int j2 = tid & 31, cg = tid >> 5;          // pos 2*j2, 8 channel groups
        for (int i = 0; i < 32; i++) {
            int c = cg + 8 * i;
            float2 v = *(const float2*)(xb + (size_t)c * HW + 2 * j2);
            *(float2*)&xt[c][2 * j2] = v;
        }
    }
    __syncthreads();
    float a0 = br[2 * wv], a1 = br[2 * wv + 1];
    for (int c = 0; c < CCH; c++) {
        float xv = xt[c][lane];
        a0 = fmaf(xv, wr[c][2 * wv], a0);
        a1 = fmaf(xv, wr[c][2 * wv + 1], a1);
    }
    lg[lane][2 * wv] = a0;
    lg[lane][2 * wv + 1] = a1;
    __syncthreads();
    if (wv == 0) {
        float v0 = -1e30f, v1 = -1e30f; int i0 = 0, i1 = 0;
        for (int e = 0; e < NE; e++) {
            float l = lg[lane][e];
            if (l > v0)      { v1 = v0; i1 = i0; v0 = l; i0 = e; }
            else if (l > v1) { v1 = l; i1 = e; }
        }
        float e1 = expf(v1 - v0);
        float s = 1.0f + e1;
        wts[n0 + lane] = make_float2(1.0f / s, e1 / s);
        pair[n0 + lane] = i0 | (i1 << 8);
        atomicAdd(&lc[i0], 1);
        atomicAdd(&lc[i1], 1);
    }
    __syncthreads();
    if (tid < NE && lc[tid] > 0) atomicAdd(&meta[tid], lc[tid]);
    for (int r = 0; r < 64; r++)
        tokens[(size_t)(n0 + r) * CCH + tid] = __float2bfloat16(xt[tid][r]);
}

// ---------------- K2: scatter tokens into per-expert lists (scan fused) -----
// meta: [0..8) counts, [8..16) cursors, [16..25) offsets, [25..34) tilestart, [34] total
// 64-token tiles (matches k_expert r0 = tile<<6).
__global__ __launch_bounds__(256) void k_scatter(
    const int* __restrict__ pair, const float2* __restrict__ wts,
    int* __restrict__ meta, int* __restrict__ assign_tok, float* __restrict__ assign_w,
    int2* __restrict__ tok_slots)
{
    __shared__ int lcount[NE];
    __shared__ int lbase[NE];
    __shared__ int soff[NE];
    int tid = threadIdx.x;
    int n = blockIdx.x * 256 + tid;
    if (tid < NE) lcount[tid] = 0;
    __syncthreads();
    int pr = pair[n];
    int e0 = pr & 0xff, e1 = (pr >> 8) & 0xff;
    int p0 = atomicAdd(&lcount[e0], 1);
    int p1 = atomicAdd(&lcount[e1], 1);
    __syncthreads();
    if (tid == 0) {
        int off = 0, toff = 0;
        for (int ee = 0; ee < NE; ee++) {
            soff[ee] = off;
            int c = meta[ee];
            if (blockIdx.x == 0) { meta[16 + ee] = off; meta[25 + ee] = toff; }
            off += c;
            toff += (c + 63) >> 6;
        }
        if (blockIdx.x == 0) { meta[24] = off; meta[33] = toff; meta[34] = toff; }
    }
    if (tid < NE) lbase[tid] = atomicAdd(&meta[8 + tid], lcount[tid]);
    __syncthreads();
    float2 w = wts[n];
    int s0 = soff[e0] + lbase[e0] + p0;
    int s1 = soff[e1] + lbase[e1] + p1;
    assign_tok[s0] = n; assign_w[s0] = w.x;
    assign_tok[s1] = n; assign_w[s1] = w.y;
    tok_slots[n] = make_int2(s0, s1);
}

// ---------------- K3: grouped fused MLP (Round-1 version: 173 us known-good) -
__global__ __launch_bounds__(512, 4) void k_expert(
    const __hip_bfloat16* __restrict__ tokens,
    const __hip_bfloat16* __restrict__ w1t,   // (E, HID, C)  = W1^T per expert
    const __hip_bfloat16* __restrict__ w2t,   // (E, C, HID)  = W2^T per expert
    const float* __restrict__ b1, const float* __restrict__ b2,
    const int* __restrict__ meta,
    const int* __restrict__ assign_tok, const float* __restrict__ assign_w,
    __hip_bfloat16* __restrict__ ybuf)
{
    // A tile, frag-linear: 16B unit U = mt*512 + (kk*4+quad)*16 + l15
    __shared__ __align__(16) __hip_bfloat16 Af[64 * 256];      // 32 KB
    __shared__ __align__(16) __hip_bfloat16 Hs[64 * PADH];     // 33.3 KB
    __shared__ float wrow[64];
    __shared__ int trow[64];

    int total = meta[34];
    int bid = blockIdx.x;
    if (bid >= total) return;
    int e = 0;
    while (e < 7 && bid >= meta[25 + e + 1]) e++;
    int tile = bid - meta[25 + e];
    int cnt = meta[e];
    int r0 = tile << 6;
    int abase = meta[16 + e] + r0;
    int nrows = cnt - r0; if (nrows > 64) nrows = 64;

    int tid = threadIdx.x;
    if (tid < 64) {
        if (tid < nrows) { trow[tid] = assign_tok[abase + tid]; wrow[tid] = assign_w[abase + tid]; }
        else             { trow[tid] = 0; wrow[tid] = 0.0f; }
    }
    __syncthreads();

    // ---- stage A tile into LDS (frag-linear; lane-linear writes => no conflicts)
    {
        uint4* dst = (uint4*)Af;
#pragma unroll
        for (int j = 0; j < 4; j++) {
            int row = j * 16 + (tid & 15);
            int chunk = (tid >> 4) & 31;
            dst[j * 512 + tid] = ((const uint4*)(tokens + (size_t)trow[row] * CCH))[chunk];
        }
    }

    int lane = tid & 63, wv = tid >> 6;      // wv in [0,8)
    int quad = lane >> 4, l15 = lane & 15;

    const __hip_bfloat16* w1e = w1t + (size_t)e * HID * CCH;
    const __hip_bfloat16* w2e = w2t + (size_t)e * CCH * HID;
    const float* b1e = b1 + e * HID;
    const float* b2e = b2 + e * CCH;

    const s16x8* apb = (const s16x8*)Af + quad * 16 + l15;   // + mt*512 + kk*64

    // GEMM1 B row pointers for both halves (h -> compile-time via unroll)
    const s16x8* bq0h[2]; const s16x8* bq1h[2];
#pragma unroll
    for (int h = 0; h < 2; h++) {
        int c0 = h * 256 + wv * 32;
        bq0h[h] = (const s16x8*)(w1e + (size_t)(c0)      * CCH + (size_t)l15 * CCH + quad * 8);
        bq1h[h] = (const s16x8*)(w1e + (size_t)(c0 + 16) * CCH + (size_t)l15 * CCH + quad * 8);
    }

    f32x4 oacc[4][2];
#pragma unroll
    for (int i = 0; i < 4; i++)
#pragma unroll
        for (int j = 0; j < 2; j++) oacc[i][j] = (f32x4){0.f, 0.f, 0.f, 0.f};

    // issue h=0 GEMM1 first B-frags and epilogue biases before the A barrier
    s16x8 bf0 = bq0h[0][0], bf1 = bq1h[0][0];
    float ob0 = b2e[wv * 32 + l15];
    float ob1 = b2e[wv * 32 + 16 + l15];

    __syncthreads();   // A tile visible (barrier drain also completes bf0/bf1)

#pragma unroll
    for (int h = 0; h < 2; h++) {
        const s16x8* bq0 = bq0h[h];
        const s16x8* bq1 = bq1h[h];

        f32x4 hacc[4][2];
#pragma unroll
        for (int i = 0; i < 4; i++)
#pragma unroll
            for (int j = 0; j < 2; j++) hacc[i][j] = (f32x4){0.f, 0.f, 0.f, 0.f};

        // ---- GEMM1: hacc[mt][nt] over K=256
#pragma unroll
        for (int kk = 0; kk < 8; kk++) {
            s16x8 bn0, bn1;
            if (kk < 7) { bn0 = bq0[(kk + 1) * 4]; bn1 = bq1[(kk + 1) * 4]; }
            s16x8 af[4];
#pragma unroll
            for (int mt = 0; mt < 4; mt++) af[mt] = apb[mt * 512 + kk * 4 * 16];
            __builtin_amdgcn_s_setprio(1);
#pragma unroll
            for (int mt = 0; mt < 4; mt++) {
                hacc[mt][0] = __builtin_amdgcn_mfma_f32_16x16x32_bf16(af[mt], bf0, hacc[mt][0], 0, 0, 0);
                hacc[mt][1] = __builtin_amdgcn_mfma_f32_16x16x32_bf16(af[mt], bf1, hacc[mt][1], 0, 0, 0);
            }
            __builtin_amdgcn_s_setprio(0);
            bf0 = bn0; bf1 = bn1;
        }

        // issue next-phase operands BEFORE the barrier so the drain completes them
        const s16x8* b2q0 = (const s16x8*)(w2e + (size_t)(wv * 32      + l15) * HID + h * 256 + quad * 8);
        const s16x8* b2q1 = (const s16x8*)(w2e + (size_t)(wv * 32 + 16 + l15) * HID + h * 256 + quad * 8);
        s16x8 cf0 = b2q0[0], cf1 = b2q1[0];
        float biasA = b1e[h * 256 + wv * 32 + l15];
        float biasB = b1e[h * 256 + wv * 32 + 16 + l15];
        if (h == 0) { bf0 = bq0h[1][0]; bf1 = bq1h[1][0]; }

        __syncthreads();   // (h=1: GEMM2 of h=0 done reading Hs)
        // ---- bias + fast GELU -> Hs (local col cl in [0,256))
#pragma unroll
        for (int nt = 0; nt < 2; nt++) {
            int cl = wv * 32 + nt * 16 + l15;
            float bias = nt ? biasB : biasA;
#pragma unroll
            for (int mt = 0; mt < 4; mt++)
#pragma unroll
                for (int r = 0; r < 4; r++) {
                    int row = mt * 16 + quad * 4 + r;
                    float v = hacc[mt][nt][r] + bias;
                    Hs[row * PADH + cl] = __float2bfloat16(fast_gelu(v));
                }
        }
        __syncthreads();

        // ---- GEMM2: A = Hs rows (LDS), B = W2^T rows (global/L2), K=256
#pragma unroll
        for (int kk = 0; kk < 8; kk++) {
            s16x8 cn0, cn1;
            if (kk < 7) { cn0 = b2q0[(kk + 1) * 4]; cn1 = b2q1[(kk + 1) * 4]; }
            s16x8 hf[4];
#pragma unroll
            for (int mt = 0; mt < 4; mt++)
                hf[mt] = *(const s16x8*)(Hs + (mt * 16 + l15) * PADH + kk * 32 + quad * 8);
            __builtin_amdgcn_s_setprio(1);
#pragma unroll
            for (int mt = 0; mt < 4; mt++) {
                oacc[mt][0] = __builtin_amdgcn_mfma_f32_16x16x32_bf16(hf[mt], cf0, oacc[mt][0], 0, 0, 0);
                oacc[mt][1] = __builtin_amdgcn_mfma_f32_16x16x32_bf16(hf[mt], cf1, oacc[mt][1], 0, 0, 0);
            }
            __builtin_amdgcn_s_setprio(0);
            cf0 = cn0; cf1 = cn1;
        }
        if (h == 0) __syncthreads();   // before h=1 GELU overwrites Hs
    }

    // ---- epilogue: (acc + b2) * route_weight -> ybuf[slot][c] bf16
#pragma unroll
    for (int nt = 0; nt < 2; nt++) {
        int cc = wv * 32 + nt * 16 + l15;
        float bias = nt ? ob1 : ob0;
#pragma unroll
        for (int mt = 0; mt < 4; mt++) {
#pragma unroll
            for (int r = 0; r < 4; r++) {
                int row = mt * 16 + quad * 4 + r;
                if (row < nrows) {
                    float v = (oacc[mt][nt][r] + bias) * wrow[row];
                    ybuf[(size_t)(abase + row) * CCH + cc] = __float2bfloat16(v);
                }
            }
        }
    }
}

// ---------------- K4: combine two expert outputs, transpose back, residual --
// 32-token tiles: LDS 33.8 KB -> 4 blocks/CU (was 66.5 KB / 2). Gather uses
// 16B/lane ushort8 loads (512 B per row per instr); write phase float4 on x/out.
__global__ __launch_bounds__(256) void k_combine(
    const float* __restrict__ x, const __hip_bfloat16* __restrict__ ybuf,
    const int2* __restrict__ tok_slots, const float* __restrict__ scale,
    float* __restrict__ out)
{
    __shared__ float moe[CCH][33];   // [channel][token], 33.8 KB
    __shared__ int2 slots[32];
    int tid = threadIdx.x;
    int n0 = blockIdx.x * 32;
    if (tid < 32) slots[tid] = tok_slots[n0 + tid];
    __syncthreads();
#pragma unroll
    for (int it = 0; it < 2; it++) {
        int r = (tid >> 4) + 16 * it;
        int g = tid & 15;                      // 16 channel groups of 16
        int2 s = slots[r];
        const u16x8* px = (const u16x8*)(ybuf + (size_t)s.x * CCH + 16 * g);
        const u16x8* py = (const u16x8*)(ybuf + (size_t)s.y * CCH + 16 * g);
        u16x8 ax0 = px[0], ax1 = px[1], ay0 = py[0], ay1 = py[1];
#pragma unroll
        for (int k = 0; k < 8; k++) {
            moe[16 * g + k][r]     = bfbits2f(ax0[k]) + bfbits2f(ay0[k]);
            moe[16 * g + 8 + k][r] = bfbits2f(ax1[k]) + bfbits2f(ay1[k]);
        }
    }
    __syncthreads();
    float sc = scale[0];
    int b = n0 >> 12, p0 = n0 & 4095;
    const float* xb = x + (size_t)b * CCH * HW + p0;
    float* ob = out + (size_t)b * CCH * HW + p0;
    int j = tid & 7, cbase = tid >> 3;         // pos 4j, 32 channels per iter
#pragma unroll
    for (int i = 0; i < 8; i++) {
        int c = cbase + 32 * i;
        float4 xv = *(const float4*)(xb + (size_t)c * HW + 4 * j);
        float4 o;
        o.x = xv.x + sc * moe[c][4 * j];
        o.y = xv.y + sc * moe[c][4 * j + 1];
        o.z = xv.z + sc * moe[c][4 * j + 2];
        o.w = xv.w + sc * moe[c][4 * j + 3];
        *(float4*)(ob + (size_t)c * HW + 4 * j) = o;
    }
}

// ---------------- launch ----------------------------------------------------
extern "C" void kernel_launch(void* const* d_in, const int* in_sizes, int n_in,
                              void* d_out, int out_size, void* d_ws, size_t ws_size,
                              hipStream_t stream)
{
    const float* x     = (const float*)d_in[0];
    const float* Wr    = (const float*)d_in[1];
    const float* br    = (const float*)d_in[2];
    const float* W1    = (const float*)d_in[3];
    const float* b1    = (const float*)d_in[4];
    const float* W2    = (const float*)d_in[5];
    const float* b2    = (const float*)d_in[6];
    const float* scale = (const float*)d_in[7];
    float* out = (float*)d_out;

    char* ws = (char*)d_ws;
    __hip_bfloat16* tokens = (__hip_bfloat16*)(ws);                 // 33,554,432 B
    __hip_bfloat16* w1t    = (__hip_bfloat16*)(ws + 33554432);      //  2,097,152 B
    __hip_bfloat16* w2t    = (__hip_bfloat16*)(ws + 35651584);      //  2,097,152 B
    __hip_bfloat16* ybuf   = (__hip_bfloat16*)(ws + 37748736);      // 67,108,864 B
    int*    assign_tok = (int*)   (ws + 104857600);                 //    524,288 B
    float*  assign_w   = (float*) (ws + 105381888);                 //    524,288 B
    int2*   tok_slots  = (int2*)  (ws + 105906176);                 //    524,288 B
    int*    pair       = (int*)   (ws + 106430464);                 //    262,144 B
    float2* wts        = (float2*)(ws + 106692608);                 //    524,288 B
    int*    meta       = (int*)   (ws + 107216896);                 //        256 B

    k_transpose_both<<<512, 256, 0, stream>>>(W1, W2, w1t, w2t, meta);
    k_router<<<1024, 256, 0, stream>>>(x, Wr, br, tokens, pair, wts, meta);
    k_scatter<<<256, 256, 0, stream>>>(pair, wts, meta, assign_tok, assign_w, tok_slots);
    k_expert<<<2056, 512, 0, stream>>>(tokens, w1t, w2t, b1, b2, meta,
                                       assign_tok, assign_w, ybuf);
    k_combine<<<2048, 256, 0, stream>>>(x, ybuf, tok_slots, scale, out);
}

// Round 4
// 339.556 us; speedup vs baseline: 1.3736x; 1.0049x over previous
//
#include <hip/hip_runtime.h>
#include <hip/hip_bf16.h>
#include <math.h>

#define HW   4096
#define CCH  256
#define NE   8
#define HID  512
#define NTOK 65536
#define PADH 260   // Hs row pitch (elems): +4 pad -> conflict-free writes, 4-way reads

typedef short s16x8 __attribute__((ext_vector_type(8)));
typedef float f32x4 __attribute__((ext_vector_type(4)));
typedef unsigned short u16x8 __attribute__((ext_vector_type(8)));

// Fast exact-enough GELU: v * sigmoid(2u), u = 0.79788456*(v + 0.044715 v^3).
__device__ __forceinline__ float fast_gelu(float v) {
    float v2 = v * v;
    float s  = v * fmaf(0.10294324f, v2, 2.3022079f);  // 2*log2e*0.79788456*(v+0.044715v^3)
    float e  = exp2f(-s);                               // = exp(-2u)
    return v * __builtin_amdgcn_rcpf(1.0f + e);         // v * sigmoid(2u)
}

__device__ __forceinline__ float bfbits2f(unsigned short h) {
    return __uint_as_float(((unsigned)h) << 16);
}

// ---------------- K transpose+cast for BOTH weights (+ meta zero) -----------
// blocks [0,256): W1 (E,256,512)->(E,512,256); blocks [256,512): W2 -> (E,256,512)
__global__ __launch_bounds__(256) void k_transpose_both(
    const float* __restrict__ W1, const float* __restrict__ W2,
    __hip_bfloat16* __restrict__ w1t, __hip_bfloat16* __restrict__ w2t,
    int* __restrict__ meta)
{
    __shared__ float t[64][65];
    if (blockIdx.x == 0 && threadIdx.x < 16) meta[threadIdx.x] = 0;  // counts+cursors
    int bb = blockIdx.x;
    const float* in; __hip_bfloat16* out; int R, CC;
    if (bb < 256) { in = W1; out = w1t; R = 256; CC = 512; }
    else          { in = W2; out = w2t; R = 512; CC = 256; bb -= 256; }
    int tilesC = CC >> 6;
    int per = (R >> 6) * tilesC;
    int e = bb / per, tt = bb % per;
    int r0 = (tt / tilesC) << 6, c0 = (tt % tilesC) << 6;
    const float* ip = in + (size_t)e * R * CC;
    __hip_bfloat16* op = out + (size_t)e * R * CC;
    int lane = threadIdx.x & 63, g = threadIdx.x >> 6;
    for (int i = 0; i < 16; i++) {
        int r = i * 4 + g;
        t[r][lane] = ip[(size_t)(r0 + r) * CC + c0 + lane];
    }
    __syncthreads();
    for (int i = 0; i < 16; i++) {
        int r = i * 4 + g;
        op[(size_t)(c0 + r) * R + r0 + lane] = __float2bfloat16(t[lane][r]);
    }
}

// ---------------- K0: x transpose -> tokens bf16, fp32 router, top2 ---------
__global__ __launch_bounds__(256) void k_router(
    const float* __restrict__ x, const float* __restrict__ Wr, const float* __restrict__ br,
    __hip_bfloat16* __restrict__ tokens, int* __restrict__ pair, float2* __restrict__ wts,
    int* __restrict__ meta /* counts at [0..8) */)
{
    __shared__ float xt[CCH][66];   // pitch 66: float2-aligned rows, 2-way banks on reads
    __shared__ float wr[CCH][NE];
    __shared__ float lg[64][NE];
    __shared__ int lc[NE];
    int tid = threadIdx.x;
    int n0 = blockIdx.x * 64;
    int b = n0 >> 12, p0 = n0 & 4095;
    const float* xb = x + (size_t)b * CCH * HW + p0;
    for (int i = tid; i < CCH * NE; i += 256) ((float*)wr)[i] = Wr[i];
    if (tid < NE) lc[tid] = 0;
    int lane = tid & 63, wv = tid >> 6;
    // float2-vectorized staged read: 32 iterations (was 64 scalar)
    {
        int j2 = tid & 31, cg = tid >> 5;          // pos 2*j2, 8 channel groups
        for (int i = 0; i < 32; i++) {
            int c = cg + 8 * i;
            float2 v = *(const float2*)(xb + (size_t)c * HW + 2 * j2);
            *(float2*)&xt[c][2 * j2] = v;
        }
    }
    __syncthreads();
    float a0 = br[2 * wv], a1 = br[2 * wv + 1];
    for (int c = 0; c < CCH; c++) {
        float xv = xt[c][lane];
        a0 = fmaf(xv, wr[c][2 * wv], a0);
        a1 = fmaf(xv, wr[c][2 * wv + 1], a1);
    }
    lg[lane][2 * wv] = a0;
    lg[lane][2 * wv + 1] = a1;
    __syncthreads();
    if (wv == 0) {
        float v0 = -1e30f, v1 = -1e30f; int i0 = 0, i1 = 0;
        for (int e = 0; e < NE; e++) {
            float l = lg[lane][e];
            if (l > v0)      { v1 = v0; i1 = i0; v0 = l; i0 = e; }
            else if (l > v1) { v1 = l; i1 = e; }
        }
        float e1 = expf(v1 - v0);
        float s = 1.0f + e1;
        wts[n0 + lane] = make_float2(1.0f / s, e1 / s);
        pair[n0 + lane] = i0 | (i1 << 8);
        atomicAdd(&lc[i0], 1);
        atomicAdd(&lc[i1], 1);
    }
    __syncthreads();
    if (tid < NE && lc[tid] > 0) atomicAdd(&meta[tid], lc[tid]);
    for (int r = 0; r < 64; r++)
        tokens[(size_t)(n0 + r) * CCH + tid] = __float2bfloat16(xt[tid][r]);
}

// ---------------- K2: scatter tokens into per-expert lists (scan fused) -----
// meta: [0..8) counts, [8..16) cursors, [16..25) offsets, [25..34) tilestart, [34] total
// 64-token tiles (matches k_expert r0 = tile<<6).
__global__ __launch_bounds__(256) void k_scatter(
    const int* __restrict__ pair, const float2* __restrict__ wts,
    int* __restrict__ meta, int* __restrict__ assign_tok, float* __restrict__ assign_w,
    int2* __restrict__ tok_slots)
{
    __shared__ int lcount[NE];
    __shared__ int lbase[NE];
    __shared__ int soff[NE];
    int tid = threadIdx.x;
    int n = blockIdx.x * 256 + tid;
    if (tid < NE) lcount[tid] = 0;
    __syncthreads();
    int pr = pair[n];
    int e0 = pr & 0xff, e1 = (pr >> 8) & 0xff;
    int p0 = atomicAdd(&lcount[e0], 1);
    int p1 = atomicAdd(&lcount[e1], 1);
    __syncthreads();
    if (tid == 0) {
        int off = 0, toff = 0;
        for (int ee = 0; ee < NE; ee++) {
            soff[ee] = off;
            int c = meta[ee];
            if (blockIdx.x == 0) { meta[16 + ee] = off; meta[25 + ee] = toff; }
            off += c;
            toff += (c + 63) >> 6;
        }
        if (blockIdx.x == 0) { meta[24] = off; meta[33] = toff; meta[34] = toff; }
    }
    if (tid < NE) lbase[tid] = atomicAdd(&meta[8 + tid], lcount[tid]);
    __syncthreads();
    float2 w = wts[n];
    int s0 = soff[e0] + lbase[e0] + p0;
    int s1 = soff[e1] + lbase[e1] + p1;
    assign_tok[s0] = n; assign_w[s0] = w.x;
    assign_tok[s1] = n; assign_w[s1] = w.y;
    tok_slots[n] = make_int2(s0, s1);
}

// ---------------- K3: grouped fused MLP (the hot kernel) --------------------
// Round-4 changes vs the 173us version:
//  * XCD-aware bijective swizzle (grid 2056 = 8*257): each XCD gets 257
//    CONSECUTIVE tiles (~1-2 experts, <=1MB weights) -> W1/W2 L2-resident,
//    B-load latency ~600(L3) -> ~200(L2) cyc, coverable by depth-1 prefetch.
//  * 2 redundant barriers removed (pre-GELU@h0, end@h0): program order makes
//    them unnecessary; GEMM1-h1 now overlaps GEMM2-h0 stragglers.
__global__ __launch_bounds__(512, 4) void k_expert(
    const __hip_bfloat16* __restrict__ tokens,
    const __hip_bfloat16* __restrict__ w1t,   // (E, HID, C)  = W1^T per expert
    const __hip_bfloat16* __restrict__ w2t,   // (E, C, HID)  = W2^T per expert
    const float* __restrict__ b1, const float* __restrict__ b2,
    const int* __restrict__ meta,
    const int* __restrict__ assign_tok, const float* __restrict__ assign_w,
    __hip_bfloat16* __restrict__ ybuf)
{
    // A tile, frag-linear: 16B unit U = mt*512 + (kk*4+quad)*16 + l15
    __shared__ __align__(16) __hip_bfloat16 Af[64 * 256];      // 32 KB
    __shared__ __align__(16) __hip_bfloat16 Hs[64 * PADH];     // 33.3 KB
    __shared__ float wrow[64];
    __shared__ int trow[64];

    int total = meta[34];
    // XCD swizzle: grid 2056 = 8 XCDs x 257 contiguous tiles (bijective)
    int bid = (blockIdx.x & 7) * 257 + (blockIdx.x >> 3);
    if (bid >= total) return;
    int e = 0;
    while (e < 7 && bid >= meta[25 + e + 1]) e++;
    int tile = bid - meta[25 + e];
    int cnt = meta[e];
    int r0 = tile << 6;
    int abase = meta[16 + e] + r0;
    int nrows = cnt - r0; if (nrows > 64) nrows = 64;

    int tid = threadIdx.x;
    if (tid < 64) {
        if (tid < nrows) { trow[tid] = assign_tok[abase + tid]; wrow[tid] = assign_w[abase + tid]; }
        else             { trow[tid] = 0; wrow[tid] = 0.0f; }
    }
    __syncthreads();

    // ---- stage A tile into LDS (frag-linear; lane-linear writes => no conflicts)
    {
        uint4* dst = (uint4*)Af;
#pragma unroll
        for (int j = 0; j < 4; j++) {
            int row = j * 16 + (tid & 15);
            int chunk = (tid >> 4) & 31;
            dst[j * 512 + tid] = ((const uint4*)(tokens + (size_t)trow[row] * CCH))[chunk];
        }
    }

    int lane = tid & 63, wv = tid >> 6;      // wv in [0,8)
    int quad = lane >> 4, l15 = lane & 15;

    const __hip_bfloat16* w1e = w1t + (size_t)e * HID * CCH;
    const __hip_bfloat16* w2e = w2t + (size_t)e * CCH * HID;
    const float* b1e = b1 + e * HID;
    const float* b2e = b2 + e * CCH;

    const s16x8* apb = (const s16x8*)Af + quad * 16 + l15;   // + mt*512 + kk*64

    // GEMM1 B row pointers for both halves (h -> compile-time via unroll)
    const s16x8* bq0h[2]; const s16x8* bq1h[2];
#pragma unroll
    for (int h = 0; h < 2; h++) {
        int c0 = h * 256 + wv * 32;
        bq0h[h] = (const s16x8*)(w1e + (size_t)(c0)      * CCH + (size_t)l15 * CCH + quad * 8);
        bq1h[h] = (const s16x8*)(w1e + (size_t)(c0 + 16) * CCH + (size_t)l15 * CCH + quad * 8);
    }

    f32x4 oacc[4][2];
#pragma unroll
    for (int i = 0; i < 4; i++)
#pragma unroll
        for (int j = 0; j < 2; j++) oacc[i][j] = (f32x4){0.f, 0.f, 0.f, 0.f};

    // issue h=0 GEMM1 first B-frags and epilogue biases before the A barrier
    s16x8 bf0 = bq0h[0][0], bf1 = bq1h[0][0];
    float ob0 = b2e[wv * 32 + l15];
    float ob1 = b2e[wv * 32 + 16 + l15];

    __syncthreads();   // A tile visible (barrier drain also completes bf0/bf1)

#pragma unroll
    for (int h = 0; h < 2; h++) {
        const s16x8* bq0 = bq0h[h];
        const s16x8* bq1 = bq1h[h];

        f32x4 hacc[4][2];
#pragma unroll
        for (int i = 0; i < 4; i++)
#pragma unroll
            for (int j = 0; j < 2; j++) hacc[i][j] = (f32x4){0.f, 0.f, 0.f, 0.f};

        // ---- GEMM1: hacc[mt][nt] over K=256
#pragma unroll
        for (int kk = 0; kk < 8; kk++) {
            s16x8 bn0, bn1;
            if (kk < 7) { bn0 = bq0[(kk + 1) * 4]; bn1 = bq1[(kk + 1) * 4]; }
            s16x8 af[4];
#pragma unroll
            for (int mt = 0; mt < 4; mt++) af[mt] = apb[mt * 512 + kk * 4 * 16];
            __builtin_amdgcn_s_setprio(1);
#pragma unroll
            for (int mt = 0; mt < 4; mt++) {
                hacc[mt][0] = __builtin_amdgcn_mfma_f32_16x16x32_bf16(af[mt], bf0, hacc[mt][0], 0, 0, 0);
                hacc[mt][1] = __builtin_amdgcn_mfma_f32_16x16x32_bf16(af[mt], bf1, hacc[mt][1], 0, 0, 0);
            }
            __builtin_amdgcn_s_setprio(0);
            bf0 = bn0; bf1 = bn1;
        }

        // issue next-phase operands early (completed under GELU / barrier drain)
        const s16x8* b2q0 = (const s16x8*)(w2e + (size_t)(wv * 32      + l15) * HID + h * 256 + quad * 8);
        const s16x8* b2q1 = (const s16x8*)(w2e + (size_t)(wv * 32 + 16 + l15) * HID + h * 256 + quad * 8);
        s16x8 cf0 = b2q0[0], cf1 = b2q1[0];
        float biasA = b1e[h * 256 + wv * 32 + l15];
        float biasB = b1e[h * 256 + wv * 32 + 16 + l15];
        if (h == 0) { bf0 = bq0h[1][0]; bf1 = bq1h[1][0]; }

        // Barrier needed only at h=1: waves passing it have finished their
        // GEMM2-h0 Hs reads (program order), so GELU-h1 may overwrite Hs.
        // At h=0 Hs is untouched since block start -> no barrier.
        if (h == 1) __syncthreads();

        // ---- bias + fast GELU -> Hs (local col cl in [0,256))
#pragma unroll
        for (int nt = 0; nt < 2; nt++) {
            int cl = wv * 32 + nt * 16 + l15;
            float bias = nt ? biasB : biasA;
#pragma unroll
            for (int mt = 0; mt < 4; mt++)
#pragma unroll
                for (int r = 0; r < 4; r++) {
                    int row = mt * 16 + quad * 4 + r;
                    float v = hacc[mt][nt][r] + bias;
                    Hs[row * PADH + cl] = __float2bfloat16(fast_gelu(v));
                }
        }
        __syncthreads();   // Hs complete before GEMM2 reads

        // ---- GEMM2: A = Hs rows (LDS), B = W2^T rows (global/L2), K=256
#pragma unroll
        for (int kk = 0; kk < 8; kk++) {
            s16x8 cn0, cn1;
            if (kk < 7) { cn0 = b2q0[(kk + 1) * 4]; cn1 = b2q1[(kk + 1) * 4]; }
            s16x8 hf[4];
#pragma unroll
            for (int mt = 0; mt < 4; mt++)
                hf[mt] = *(const s16x8*)(Hs + (mt * 16 + l15) * PADH + kk * 32 + quad * 8);
            __builtin_amdgcn_s_setprio(1);
#pragma unroll
            for (int mt = 0; mt < 4; mt++) {
                oacc[mt][0] = __builtin_amdgcn_mfma_f32_16x16x32_bf16(hf[mt], cf0, oacc[mt][0], 0, 0, 0);
                oacc[mt][1] = __builtin_amdgcn_mfma_f32_16x16x32_bf16(hf[mt], cf1, oacc[mt][1], 0, 0, 0);
            }
            __builtin_amdgcn_s_setprio(0);
            cf0 = cn0; cf1 = cn1;
        }
        // no barrier at h=0 end: the h=1 pre-GELU barrier protects Hs
    }

    // ---- epilogue: (acc + b2) * route_weight -> ybuf[slot][c] bf16
#pragma unroll
    for (int nt = 0; nt < 2; nt++) {
        int cc = wv * 32 + nt * 16 + l15;
        float bias = nt ? ob1 : ob0;
#pragma unroll
        for (int mt = 0; mt < 4; mt++) {
#pragma unroll
            for (int r = 0; r < 4; r++) {
                int row = mt * 16 + quad * 4 + r;
                if (row < nrows) {
                    float v = (oacc[mt][nt][r] + bias) * wrow[row];
                    ybuf[(size_t)(abase + row) * CCH + cc] = __float2bfloat16(v);
                }
            }
        }
    }
}

// ---------------- K4: combine two expert outputs, transpose back, residual --
// 32-token tiles: LDS 33.8 KB -> 4 blocks/CU. Gather uses 16B/lane ushort8
// loads; write phase float4 on x/out.
__global__ __launch_bounds__(256) void k_combine(
    const float* __restrict__ x, const __hip_bfloat16* __restrict__ ybuf,
    const int2* __restrict__ tok_slots, const float* __restrict__ scale,
    float* __restrict__ out)
{
    __shared__ float moe[CCH][33];   // [channel][token], 33.8 KB
    __shared__ int2 slots[32];
    int tid = threadIdx.x;
    int n0 = blockIdx.x * 32;
    if (tid < 32) slots[tid] = tok_slots[n0 + tid];
    __syncthreads();
#pragma unroll
    for (int it = 0; it < 2; it++) {
        int r = (tid >> 4) + 16 * it;
        int g = tid & 15;                      // 16 channel groups of 16
        int2 s = slots[r];
        const u16x8* px = (const u16x8*)(ybuf + (size_t)s.x * CCH + 16 * g);
        const u16x8* py = (const u16x8*)(ybuf + (size_t)s.y * CCH + 16 * g);
        u16x8 ax0 = px[0], ax1 = px[1], ay0 = py[0], ay1 = py[1];
#pragma unroll
        for (int k = 0; k < 8; k++) {
            moe[16 * g + k][r]     = bfbits2f(ax0[k]) + bfbits2f(ay0[k]);
            moe[16 * g + 8 + k][r] = bfbits2f(ax1[k]) + bfbits2f(ay1[k]);
        }
    }
    __syncthreads();
    float sc = scale[0];
    int b = n0 >> 12, p0 = n0 & 4095;
    const float* xb = x + (size_t)b * CCH * HW + p0;
    float* ob = out + (size_t)b * CCH * HW + p0;
    int j = tid & 7, cbase = tid >> 3;         // pos 4j, 32 channels per iter
#pragma unroll
    for (int i = 0; i < 8; i++) {
        int c = cbase + 32 * i;
        float4 xv = *(const float4*)(xb + (size_t)c * HW + 4 * j);
        float4 o;
        o.x = xv.x + sc * moe[c][4 * j];
        o.y = xv.y + sc * moe[c][4 * j + 1];
        o.z = xv.z + sc * moe[c][4 * j + 2];
        o.w = xv.w + sc * moe[c][4 * j + 3];
        *(float4*)(ob + (size_t)c * HW + 4 * j) = o;
    }
}

// ---------------- launch ----------------------------------------------------
extern "C" void kernel_launch(void* const* d_in, const int* in_sizes, int n_in,
                              void* d_out, int out_size, void* d_ws, size_t ws_size,
                              hipStream_t stream)
{
    const float* x     = (const float*)d_in[0];
    const float* Wr    = (const float*)d_in[1];
    const float* br    = (const float*)d_in[2];
    const float* W1    = (const float*)d_in[3];
    const float* b1    = (const float*)d_in[4];
    const float* W2    = (const float*)d_in[5];
    const float* b2    = (const float*)d_in[6];
    const float* scale = (const float*)d_in[7];
    float* out = (float*)d_out;

    char* ws = (char*)d_ws;
    __hip_bfloat16* tokens = (__hip_bfloat16*)(ws);                 // 33,554,432 B
    __hip_bfloat16* w1t    = (__hip_bfloat16*)(ws + 33554432);      //  2,097,152 B
    __hip_bfloat16* w2t    = (__hip_bfloat16*)(ws + 35651584);      //  2,097,152 B
    __hip_bfloat16* ybuf   = (__hip_bfloat16*)(ws + 37748736);      // 67,108,864 B
    int*    assign_tok = (int*)   (ws + 104857600);                 //    524,288 B
    float*  assign_w   = (float*) (ws + 105381888);                 //    524,288 B
    int2*   tok_slots  = (int2*)  (ws + 105906176);                 //    524,288 B
    int*    pair       = (int*)   (ws + 106430464);                 //    262,144 B
    float2* wts        = (float2*)(ws + 106692608);                 //    524,288 B
    int*    meta       = (int*)   (ws + 107216896);                 //        256 B

    k_transpose_both<<<512, 256, 0, stream>>>(W1, W2, w1t, w2t, meta);
    k_router<<<1024, 256, 0, stream>>>(x, Wr, br, tokens, pair, wts, meta);
    k_scatter<<<256, 256, 0, stream>>>(pair, wts, meta, assign_tok, assign_w, tok_slots);
    k_expert<<<2056, 512, 0, stream>>>(tokens, w1t, w2t, b1, b2, meta,
                                       assign_tok, assign_w, ybuf);
    k_combine<<<2048, 256, 0, stream>>>(x, ybuf, tok_slots, scale, out);
}